// Round 1
// baseline (2358.420 us; speedup 1.0000x reference)
//
#include <hip/hip_runtime.h>
#include <math.h>

#define Tn   64
#define BSn  64
#define DIMn 1024
#define EMBn 512
#define SRCn 512
#define G4n  4096   // 4*DIM

typedef __attribute__((ext_vector_type(4))) float  f4;
typedef __attribute__((ext_vector_type(8))) __bf16 b8;
typedef __attribute__((ext_vector_type(4))) __bf16 b4;

__device__ __forceinline__ f4 mfma16(b8 a, b8 b, f4 c) {
    return __builtin_amdgcn_mfma_f32_16x16x32_bf16(a, b, c, 0, 0, 0);
}
__device__ __forceinline__ float sigm(float x) { return 1.0f / (1.0f + __expf(-x)); }
__device__ __forceinline__ b4 tobf4(f4 v) {
    b4 r; r[0]=(__bf16)v[0]; r[1]=(__bf16)v[1]; r[2]=(__bf16)v[2]; r[3]=(__bf16)v[3]; return r;
}
__device__ __forceinline__ f4 fromb4(b4 v) {
    f4 r; r[0]=(float)v[0]; r[1]=(float)v[1]; r[2]=(float)v[2]; r[3]=(float)v[3]; return r;
}

// ---------------------------------------------------------------------------
// Generic 64x64 wave tile GEMM: D[m][n] = sum_k A[m][k] * B[n][k]
// A: 64 rows (lda), B: 64 rows (ldb), K = KS*32.
// MFMA 16x16x32 layout: a-frag row = lane&15, k = (lane>>4)*8+j;
//                       D: col = lane&15 (B index), row = (lane>>4)*4+i (A index)
// ---------------------------------------------------------------------------
template<int KS>
__device__ __forceinline__ void wave_gemm64(const __bf16* __restrict__ A, int lda,
                                            const __bf16* __restrict__ B, int ldb,
                                            f4 acc[4][4], int lane) {
    const int m = lane & 15, q = lane >> 4;
    const __bf16* Ap = A + (size_t)m * lda + q * 8;
    const __bf16* Bp = B + (size_t)m * ldb + q * 8;
#pragma unroll 2
    for (int ks = 0; ks < KS; ++ks) {
        const int k = ks * 32;
        b8 a0 = *(const b8*)(Ap + k);
        b8 a1 = *(const b8*)(Ap + 16 * lda + k);
        b8 a2 = *(const b8*)(Ap + 32 * lda + k);
        b8 a3 = *(const b8*)(Ap + 48 * lda + k);
        b8 b0 = *(const b8*)(Bp + k);
        b8 b1 = *(const b8*)(Bp + 16 * ldb + k);
        b8 b2 = *(const b8*)(Bp + 32 * ldb + k);
        b8 b3 = *(const b8*)(Bp + 48 * ldb + k);
        acc[0][0]=mfma16(a0,b0,acc[0][0]); acc[0][1]=mfma16(a0,b1,acc[0][1]);
        acc[0][2]=mfma16(a0,b2,acc[0][2]); acc[0][3]=mfma16(a0,b3,acc[0][3]);
        acc[1][0]=mfma16(a1,b0,acc[1][0]); acc[1][1]=mfma16(a1,b1,acc[1][1]);
        acc[1][2]=mfma16(a1,b2,acc[1][2]); acc[1][3]=mfma16(a1,b3,acc[1][3]);
        acc[2][0]=mfma16(a2,b0,acc[2][0]); acc[2][1]=mfma16(a2,b1,acc[2][1]);
        acc[2][2]=mfma16(a2,b2,acc[2][2]); acc[2][3]=mfma16(a2,b3,acc[2][3]);
        acc[3][0]=mfma16(a3,b0,acc[3][0]); acc[3][1]=mfma16(a3,b1,acc[3][1]);
        acc[3][2]=mfma16(a3,b2,acc[3][2]); acc[3][3]=mfma16(a3,b3,acc[3][3]);
    }
}

// ---------------------------------------------------------------------------
// K0a: weights -> bf16, bias sum, h0 -> bf16, zero the barrier counter
// ---------------------------------------------------------------------------
__global__ void k_conv_w(const float* __restrict__ Wih, const float* __restrict__ Whh,
                         const float* __restrict__ Wenc, const float* __restrict__ Wdec,
                         const float* __restrict__ bih, const float* __restrict__ bhh,
                         const float* __restrict__ h0,
                         __bf16* __restrict__ Wihb, __bf16* __restrict__ Whhb,
                         __bf16* __restrict__ Wqdb, float* __restrict__ bsum,
                         __bf16* __restrict__ H0b, unsigned* __restrict__ cnt) {
    size_t stride = (size_t)gridDim.x * blockDim.x;
    for (size_t i = (size_t)blockIdx.x * blockDim.x + threadIdx.x; i < 4194304ull; i += stride) {
        Whhb[i] = (__bf16)Whh[i];
        if (i < 2097152ull) {
            Wihb[i] = (__bf16)Wih[i];
            Wqdb[i] = (__bf16)((i < 1048576ull) ? Wenc[i] : Wdec[i - 1048576ull]);
        }
        if (i < 65536ull) H0b[i] = (__bf16)h0[i];
        if (i < 4096ull)  bsum[i] = bih[i] + bhh[i];
        if (i == 0)       *cnt = 0u;
    }
}

// K0b: embedding gather -> bf16, layout [t*64+b][512]
__global__ __launch_bounds__(128) void k_emb(const int* __restrict__ toks,
                                             const float* __restrict__ Wemb,
                                             __bf16* __restrict__ embb) {
    int tb = blockIdx.x;
    int tok = toks[tb];
    f4 v = *(const f4*)(Wemb + (size_t)tok * EMBn + threadIdx.x * 4);
    *(b4*)(embb + (size_t)tb * EMBn + threadIdx.x * 4) = tobf4(v);
}

// K0c: h_e [n][b][d] f32 -> he_nd [b][n][d] bf16
__global__ __launch_bounds__(256) void k_he(const float* __restrict__ he, __bf16* __restrict__ hend) {
    int b = blockIdx.x >> 9, n = blockIdx.x & 511;
    int d = threadIdx.x * 4;
    f4 v = *(const f4*)(he + ((size_t)n * BSn + b) * DIMn + d);
    *(b4*)(hend + ((size_t)b * SRCn + n) * DIMn + d) = tobf4(v);
}

// ---------------------------------------------------------------------------
// K1: G_in[tb][r] = emb[tb] . W_ih[r] + b_ih[r] + b_hh[r]   (bf16 out, [tb][4096])
// A = W_ih rows (M=4096), B = emb rows (N=4096), K=512
// ---------------------------------------------------------------------------
__global__ __launch_bounds__(256) void k_gin(const __bf16* __restrict__ Wihb,
                                             const __bf16* __restrict__ embb,
                                             const float* __restrict__ bsum,
                                             __bf16* __restrict__ Gbf) {
    int wv = blockIdx.x * 4 + (threadIdx.x >> 6);
    int lane = threadIdx.x & 63, m = lane & 15, q = lane >> 4;
    int Mt = wv >> 6, Nt = wv & 63;
    const f4 Z = {0.f, 0.f, 0.f, 0.f};
    f4 acc[4][4];
#pragma unroll
    for (int i = 0; i < 4; ++i)
#pragma unroll
        for (int j = 0; j < 4; ++j) acc[i][j] = Z;
    wave_gemm64<16>(Wihb + (size_t)Mt * 64 * EMBn, EMBn,
                    embb + (size_t)Nt * 64 * EMBn, EMBn, acc, lane);
#pragma unroll
    for (int mi = 0; mi < 4; ++mi)
#pragma unroll
        for (int ni = 0; ni < 4; ++ni) {
            int r0 = Mt * 64 + mi * 16 + q * 4;
            int tb = Nt * 64 + ni * 16 + m;
            f4 v = acc[mi][ni] + *(const f4*)(bsum + r0);
            *(b4*)(Gbf + (size_t)tb * G4n + r0) = tobf4(v);
        }
}

// ---------------------------------------------------------------------------
// Manual grid barrier (64 co-resident blocks; monotone counter)
// ---------------------------------------------------------------------------
__device__ __forceinline__ void gsync(unsigned* cnt, unsigned nb, unsigned& target) {
    __syncthreads();
    if (threadIdx.x == 0) {
        __threadfence();  // release prior global stores device-wide
        __hip_atomic_fetch_add(cnt, 1u, __ATOMIC_RELEASE, __HIP_MEMORY_SCOPE_AGENT);
        target += nb;
        while (__hip_atomic_load(cnt, __ATOMIC_ACQUIRE, __HIP_MEMORY_SCOPE_AGENT) < target)
            __builtin_amdgcn_s_sleep(2);
    }
    __syncthreads();
}

// ---------------------------------------------------------------------------
// K2: sequential LSTM over t. 64 blocks x 256. Block owns 16 dims x 4 gates.
// gate[b][g*1024+d] = G_in + h_prev . W_hh[row]; MFMA: A=W rows, B=h rows.
// Writes h to out[t][b][0:1024] (f32) and Hbf[t*64+b][d] (bf16).
// ---------------------------------------------------------------------------
__global__ __launch_bounds__(256) void k_lstm(const __bf16* __restrict__ Whhb,
                                              const __bf16* __restrict__ Gbf,
                                              const __bf16* __restrict__ H0b,
                                              const float* __restrict__ c0,
                                              __bf16* __restrict__ Hbf,
                                              float* __restrict__ out,
                                              unsigned* __restrict__ cnt) {
    const int tid = threadIdx.x, w = tid >> 6, lane = tid & 63;
    const int m = lane & 15, q = lane >> 4;
    const int dblk = blockIdx.x * 16;
    const int bb = w * 16 + m;        // this thread's batch (D col)
    const int d0 = dblk + q * 4;      // first of this thread's 4 dims (D rows)
    f4 cst = *(const f4*)(c0 + (size_t)bb * DIMn + d0);
    unsigned target = 0;
    const __bf16* w0 = Whhb + ((size_t)(0 * DIMn + dblk + m)) * DIMn + q * 8;
    const __bf16* w1 = Whhb + ((size_t)(1 * DIMn + dblk + m)) * DIMn + q * 8;
    const __bf16* w2 = Whhb + ((size_t)(2 * DIMn + dblk + m)) * DIMn + q * 8;
    const __bf16* w3 = Whhb + ((size_t)(3 * DIMn + dblk + m)) * DIMn + q * 8;

    for (int t = 0; t < Tn; ++t) {
        const __bf16* hprev = t ? (Hbf + (size_t)(t - 1) * BSn * DIMn) : H0b;
        const __bf16* hp = hprev + (size_t)bb * DIMn + q * 8;
        f4 acc[4];
        const __bf16* gp = Gbf + (size_t)(t * BSn + bb) * G4n;
#pragma unroll
        for (int g = 0; g < 4; ++g) acc[g] = fromb4(*(const b4*)(gp + g * DIMn + d0));
#pragma unroll 4
        for (int k = 0; k < DIMn; k += 32) {
            b8 hb = *(const b8*)(hp + k);
            acc[0] = mfma16(*(const b8*)(w0 + k), hb, acc[0]);
            acc[1] = mfma16(*(const b8*)(w1 + k), hb, acc[1]);
            acc[2] = mfma16(*(const b8*)(w2 + k), hb, acc[2]);
            acc[3] = mfma16(*(const b8*)(w3 + k), hb, acc[3]);
        }
        f4 hv;
#pragma unroll
        for (int i = 0; i < 4; ++i) {
            float c = sigm(acc[1][i]) * cst[i] + sigm(acc[0][i]) * tanhf(acc[2][i]);
            cst[i] = c;
            hv[i] = sigm(acc[3][i]) * tanhf(c);
        }
        *(f4*)(out + (size_t)(t * BSn + bb) * 3072 + d0) = hv;
        *(b4*)(Hbf + (size_t)(t * BSn + bb) * DIMn + d0) = tobf4(hv);
        if (t != Tn - 1) gsync(cnt, gridDim.x, target);
    }
}

// ---------------------------------------------------------------------------
// K3: Q/QD = H @ [Wenc;Wdec]^T + bias. A = Wqd rows (M=2048), B = Hbf rows
// (N=4096 tb), K=1024. Writes Qbf/QDbf [b][t][d] bf16.
// ---------------------------------------------------------------------------
__global__ __launch_bounds__(256) void k_qd(const __bf16* __restrict__ Wqdb,
                                            const __bf16* __restrict__ Hbf,
                                            const float* __restrict__ benc,
                                            const float* __restrict__ bdec,
                                            __bf16* __restrict__ Qb,
                                            __bf16* __restrict__ QDb) {
    int wv = blockIdx.x * 4 + (threadIdx.x >> 6);
    int lane = threadIdx.x & 63, m = lane & 15, q = lane >> 4;
    int Mt = wv >> 6, Nt = wv & 63;
    const f4 Z = {0.f, 0.f, 0.f, 0.f};
    f4 acc[4][4];
#pragma unroll
    for (int i = 0; i < 4; ++i)
#pragma unroll
        for (int j = 0; j < 4; ++j) acc[i][j] = Z;
    wave_gemm64<32>(Wqdb + (size_t)Mt * 64 * DIMn, DIMn,
                    Hbf + (size_t)Nt * 64 * DIMn, DIMn, acc, lane);
#pragma unroll
    for (int mi = 0; mi < 4; ++mi)
#pragma unroll
        for (int ni = 0; ni < 4; ++ni) {
            int dp0 = Mt * 64 + mi * 16 + q * 4;
            int tb = Nt * 64 + ni * 16 + m;
            int t = tb >> 6, b = tb & 63;
            if (dp0 < 1024) {
                f4 v = acc[mi][ni] + *(const f4*)(benc + dp0);
                *(b4*)(Qb + ((size_t)(b * 64 + t)) * DIMn + dp0) = tobf4(v);
            } else {
                f4 v = acc[mi][ni] + *(const f4*)(bdec + (dp0 - 1024));
                *(b4*)(QDb + ((size_t)(b * 64 + t)) * DIMn + (dp0 - 1024)) = tobf4(v);
            }
        }
}

// ---------------------------------------------------------------------------
// K4: E[b][n][t] = Q[b][t] . he_nd[b][n]  (per-batch GEMM, M=t, N=n, K=1024)
// ---------------------------------------------------------------------------
__global__ __launch_bounds__(256) void k_e(const __bf16* __restrict__ Qb,
                                           const __bf16* __restrict__ hend,
                                           float* __restrict__ E) {
    int wv = blockIdx.x * 4 + (threadIdx.x >> 6);   // 512 waves: b(64) x nch(8)
    int lane = threadIdx.x & 63, m = lane & 15, q = lane >> 4;
    int b = wv >> 3, nch = wv & 7;
    const f4 Z = {0.f, 0.f, 0.f, 0.f};
    f4 acc[4][4];
#pragma unroll
    for (int i = 0; i < 4; ++i)
#pragma unroll
        for (int j = 0; j < 4; ++j) acc[i][j] = Z;
    wave_gemm64<32>(Qb + (size_t)b * 64 * DIMn, DIMn,
                    hend + ((size_t)b * SRCn + nch * 64) * DIMn, DIMn, acc, lane);
#pragma unroll
    for (int mi = 0; mi < 4; ++mi)
#pragma unroll
        for (int ni = 0; ni < 4; ++ni) {
            int t0 = mi * 16 + q * 4;
            int n = nch * 64 + ni * 16 + m;
            *(f4*)(E + ((size_t)b * SRCn + n) * 64 + t0) = acc[mi][ni];
        }
}

// K4b: fp32 recompute of q0 = h1 @ Wenc^T + benc (t=0 accuracy insurance)
__global__ __launch_bounds__(256) void k_q0(const float* __restrict__ out,
                                            const float* __restrict__ Wenc,
                                            const float* __restrict__ benc,
                                            float* __restrict__ q0) {
    int b = blockIdx.x;
    __shared__ float h1[1024];
    for (int i = threadIdx.x; i < 1024; i += 256) h1[i] = out[(size_t)b * 3072 + i];
    __syncthreads();
    for (int d = threadIdx.x; d < 1024; d += 256) {
        const float* wr = Wenc + (size_t)d * DIMn;
        float acc = benc[d];
        for (int k = 0; k < 1024; ++k) acc += h1[k] * wr[k];
        q0[(size_t)b * DIMn + d] = acc;
    }
}

// K4c: overwrite E[b][n][0] with fp32 dot q0[b] . h_e[n][b]
__global__ __launch_bounds__(256) void k_efix(const float* __restrict__ he,
                                              const float* __restrict__ q0,
                                              float* __restrict__ E) {
    int b = blockIdx.x >> 3, ng = blockIdx.x & 7;
    __shared__ float q[1024];
    for (int i = threadIdx.x; i < 1024; i += 256) q[i] = q0[(size_t)b * DIMn + i];
    __syncthreads();
    int w = threadIdx.x >> 6, lane = threadIdx.x & 63;
    for (int j = 0; j < 16; ++j) {
        int n = ng * 64 + w * 16 + j;
        const float* x = he + ((size_t)n * BSn + b) * DIMn + lane * 16;
        int k0 = lane * 16;
        float acc = 0.f;
#pragma unroll
        for (int u = 0; u < 16; ++u) acc += x[u] * q[k0 + u];
        for (int off = 32; off; off >>= 1) acc += __shfl_xor(acc, off);
        if (lane == 0) E[((size_t)b * SRCn + n) * 64] = acc;
    }
}

// ---------------------------------------------------------------------------
// K5: online-softmax-over-time recurrence per (b,n); SC[b][t][n]
// ---------------------------------------------------------------------------
__global__ void k_rec(const float* __restrict__ E, float* __restrict__ SC) {
    int idx = blockIdx.x * blockDim.x + threadIdx.x;   // 32768 = b*512+n
    int b = idx >> 9, n = idx & 511;
    const float* ep = E + (size_t)idx * 64;
    float mm = -1e30f, ss = 0.f;
    for (int t = 0; t < 64; ++t) {
        float e = ep[t];
        float m2 = fmaxf(mm, e);
        float s2 = ss * __expf(mm - m2) + __expf(e - m2);
        float sc = (t == 0) ? e : (__expf(e - m2) / s2);
        mm = m2; ss = s2;
        SC[((size_t)(b * 64 + t)) * 512 + n] = sc;
    }
}

// K6: row softmax over n, output bf16 alpha [b][t][n]
__global__ __launch_bounds__(64) void k_soft(const float* __restrict__ SC,
                                             __bf16* __restrict__ alpha) {
    const int row = blockIdx.x, lane = threadIdx.x;
    const float* p = SC + (size_t)row * 512 + lane * 8;
    float v[8];
#pragma unroll
    for (int j = 0; j < 8; ++j) v[j] = p[j];
    float mx = v[0];
#pragma unroll
    for (int j = 1; j < 8; ++j) mx = fmaxf(mx, v[j]);
    for (int off = 32; off; off >>= 1) mx = fmaxf(mx, __shfl_xor(mx, off));
    float s = 0.f;
#pragma unroll
    for (int j = 0; j < 8; ++j) { v[j] = __expf(v[j] - mx); s += v[j]; }
    for (int off = 32; off; off >>= 1) s += __shfl_xor(s, off);
    float inv = 1.f / s;
    b8 o;
#pragma unroll
    for (int j = 0; j < 8; ++j) o[j] = (__bf16)(v[j] * inv);
    *(b8*)(alpha + (size_t)row * 512 + lane * 8) = o;
}

// K7: h_e [n][b][d] f32 -> he_dn [b][d][n] bf16 (LDS tile transpose)
__global__ __launch_bounds__(256) void k_hedn(const float* __restrict__ he,
                                              __bf16* __restrict__ hedn) {
    int blk = blockIdx.x;
    int b = blk >> 9, rest = blk & 511, dt = rest >> 4, nt = rest & 15;
    int d0 = dt * 32, n0 = nt * 32;
    __shared__ float tile[32][33];
    int tx = threadIdx.x & 31, ty = threadIdx.x >> 5;
#pragma unroll
    for (int r = 0; r < 4; ++r) {
        int nl = ty + r * 8;
        tile[nl][tx] = he[(size_t)(n0 + nl) * (BSn * DIMn) + (size_t)b * DIMn + d0 + tx];
    }
    __syncthreads();
#pragma unroll
    for (int r = 0; r < 4; ++r) {
        int dl = ty + r * 8;
        hedn[((size_t)b * DIMn + d0 + dl) * SRCn + n0 + tx] = (__bf16)tile[tx][dl];
    }
}

// ---------------------------------------------------------------------------
// K8: C_e: out[t][b][1024+d] = sum_n alpha[b][t][n] * h_e[n][b][d]
// A = he_dn rows d (M=1024), B = alpha rows t (N=64), K=512.
// ---------------------------------------------------------------------------
__global__ __launch_bounds__(256) void k_ce(const __bf16* __restrict__ hedn,
                                            const __bf16* __restrict__ alpha,
                                            float* __restrict__ out) {
    int wv = blockIdx.x * 4 + (threadIdx.x >> 6);   // 1024 waves: b(64) x dch(16)
    int lane = threadIdx.x & 63, m = lane & 15, q = lane >> 4;
    int b = wv >> 4, dch = wv & 15;
    const f4 Z = {0.f, 0.f, 0.f, 0.f};
    f4 acc[4][4];
#pragma unroll
    for (int i = 0; i < 4; ++i)
#pragma unroll
        for (int j = 0; j < 4; ++j) acc[i][j] = Z;
    wave_gemm64<16>(hedn + ((size_t)b * DIMn + dch * 64) * SRCn, SRCn,
                    alpha + (size_t)b * 64 * SRCn, SRCn, acc, lane);
#pragma unroll
    for (int mi = 0; mi < 4; ++mi)
#pragma unroll
        for (int ni = 0; ni < 4; ++ni) {
            int d0 = dch * 64 + mi * 16 + q * 4;
            int t = ni * 16 + m;
            *(f4*)(out + (size_t)(t * BSn + b) * 3072 + 1024 + d0) = acc[mi][ni];
        }
}

// ---------------------------------------------------------------------------
// K9: decoder self-attention, one block per batch.
// ED = QD_b @ H_b^T (MFMA) -> masked softmax (t' < max(t,1)) -> CD = alpha @ H_b
// ---------------------------------------------------------------------------
__global__ __launch_bounds__(256) void k_dec(const __bf16* __restrict__ QDb,
                                             const __bf16* __restrict__ Hbf,
                                             float* __restrict__ out) {
    int b = blockIdx.x;
    __shared__ __attribute__((aligned(16))) char smem[46080];
    float*  ed = (float*)smem;               // [64][72] fp32 (18432 B)
    __bf16* al = (__bf16*)(smem + 36864);    // [64][72] bf16 (9216 B)
    __bf16* ht = (__bf16*)smem;              // [256][72] bf16 (36864 B) phase 3
    int tid = threadIdx.x, w = tid >> 6, lane = tid & 63;
    int m = lane & 15, q = lane >> 4;
    const f4 Z = {0.f, 0.f, 0.f, 0.f};

    { // phase 1: ED[t][t']
        f4 acc[4] = {Z, Z, Z, Z};
        const __bf16* Ap = QDb + ((size_t)(b * 64) + w * 16 + m) * DIMn + q * 8;
        for (int k = 0; k < 1024; k += 32) {
            b8 a = *(const b8*)(Ap + k);
#pragma unroll
            for (int nt = 0; nt < 4; ++nt) {
                const b8 bb = *(const b8*)(Hbf + ((size_t)((nt * 16 + m) * 64) + b) * DIMn + k + q * 8);
                acc[nt] = mfma16(a, bb, acc[nt]);
            }
        }
#pragma unroll
        for (int nt = 0; nt < 4; ++nt)
#pragma unroll
            for (int i = 0; i < 4; ++i)
                ed[(w * 16 + q * 4 + i) * 72 + nt * 16 + m] = acc[nt][i];
    }
    __syncthreads();
    // phase 2: masked row softmax -> al (bf16)
    if (tid < 64) {
        int t = tid;
        int nv = t ? t : 1;
        float mx = -1e30f;
        for (int j = 0; j < nv; ++j) mx = fmaxf(mx, ed[t * 72 + j]);
        float s = 0.f;
        for (int j = 0; j < nv; ++j) s += __expf(ed[t * 72 + j] - mx);
        float inv = 1.f / s;
        for (int j = 0; j < 64; ++j)
            al[t * 72 + j] = (__bf16)((j < nv) ? __expf(ed[t * 72 + j] - mx) * inv : 0.f);
    }
    __syncthreads();
    // phase 3: CD = alpha @ H_b, chunked over d (256 at a time)
    for (int dch = 0; dch < 4; ++dch) {
        for (int it = 0; it < 64; ++it)
            ht[tid * 72 + it] = Hbf[((size_t)(it * 64) + b) * DIMn + dch * 256 + tid];
        __syncthreads();
        f4 acc[4][4];
#pragma unroll
        for (int i = 0; i < 4; ++i)
#pragma unroll
            for (int j = 0; j < 4; ++j) acc[i][j] = Z;
#pragma unroll
        for (int kk = 0; kk < 64; kk += 32) {
            b8 a[4], bfr[4];
#pragma unroll
            for (int mi = 0; mi < 4; ++mi)
                a[mi] = *(const b8*)(ht + (size_t)(w * 64 + mi * 16 + m) * 72 + kk + q * 8);
#pragma unroll
            for (int nt = 0; nt < 4; ++nt)
                bfr[nt] = *(const b8*)(al + (size_t)(nt * 16 + m) * 72 + kk + q * 8);
#pragma unroll
            for (int mi = 0; mi < 4; ++mi)
#pragma unroll
                for (int nt = 0; nt < 4; ++nt)
                    acc[mi][nt] = mfma16(a[mi], bfr[nt], acc[mi][nt]);
        }
#pragma unroll
        for (int mi = 0; mi < 4; ++mi)
#pragma unroll
            for (int nt = 0; nt < 4; ++nt) {
                int t = nt * 16 + m;
                int d0 = dch * 256 + w * 64 + mi * 16 + q * 4;
                f4 v = (t == 0) ? Z : acc[mi][nt];
                *(f4*)(out + (size_t)(t * BSn + b) * 3072 + 2048 + d0) = v;
            }
        __syncthreads();
    }
}

// ---------------------------------------------------------------------------
extern "C" void kernel_launch(void* const* d_in, const int* in_sizes, int n_in,
                              void* d_out, int out_size, void* d_ws, size_t ws_size,
                              hipStream_t stream) {
    const int*   toks = (const int*)d_in[0];
    const float* h_e  = (const float*)d_in[1];
    const float* h0   = (const float*)d_in[2];
    const float* c0   = (const float*)d_in[3];
    const float* Wemb = (const float*)d_in[4];
    const float* Wih  = (const float*)d_in[5];
    const float* Whh  = (const float*)d_in[6];
    const float* bih  = (const float*)d_in[7];
    const float* bhh  = (const float*)d_in[8];
    const float* Wenc = (const float*)d_in[9];
    const float* benc = (const float*)d_in[10];
    const float* Wdec = (const float*)d_in[11];
    const float* bdec = (const float*)d_in[12];
    float* out = (float*)d_out;
    char* ws = (char*)d_ws;

    constexpr size_t MB = 1ull << 20;
    unsigned* cnt  = (unsigned*)(ws + 0);
    float*  bsum   = (float*)(ws + 1024);
    float*  q0     = (float*)(ws + 256 * 1024);
    __bf16* Whhb   = (__bf16*)(ws + 1 * MB);    // 8 MB
    __bf16* Wihb   = (__bf16*)(ws + 9 * MB);    // 4 MB
    __bf16* Wqdb   = (__bf16*)(ws + 13 * MB);   // 4 MB
    __bf16* embb   = (__bf16*)(ws + 17 * MB);   // 4 MB
    __bf16* H0b    = (__bf16*)(ws + 21 * MB);   // 128 KB
    __bf16* Hbf    = (__bf16*)(ws + 22 * MB);   // 8 MB
    __bf16* Qb     = (__bf16*)(ws + 30 * MB);   // 8 MB
    __bf16* QDb    = (__bf16*)(ws + 38 * MB);   // 8 MB
    __bf16* hend   = (__bf16*)(ws + 46 * MB);   // 64 MB
    __bf16* Gbf    = (__bf16*)(ws + 110 * MB);  // 32 MB (dead after k_lstm)
    float*  E      = (float*)(ws + 142 * MB);   // 8 MB (dead after k_rec)
    __bf16* hedn   = (__bf16*)(ws + 110 * MB);  // 64 MB (overlays Gbf+E, written later)
    float*  SC     = (float*)(ws + 174 * MB);   // 8 MB
    __bf16* alpha  = (__bf16*)(ws + 182 * MB);  // 4 MB  -> total 186 MB

    k_conv_w<<<dim3(4096), dim3(256), 0, stream>>>(Wih, Whh, Wenc, Wdec, bih, bhh, h0,
                                                   Wihb, Whhb, Wqdb, bsum, H0b, cnt);
    k_emb<<<dim3(4096), dim3(128), 0, stream>>>(toks, Wemb, embb);
    k_he<<<dim3(32768), dim3(256), 0, stream>>>(h_e, hend);
    k_gin<<<dim3(1024), dim3(256), 0, stream>>>(Wihb, embb, bsum, Gbf);
    k_lstm<<<dim3(64), dim3(256), 0, stream>>>(Whhb, Gbf, H0b, c0, Hbf, out, cnt);
    k_qd<<<dim3(512), dim3(256), 0, stream>>>(Wqdb, Hbf, benc, bdec, Qb, QDb);
    k_e<<<dim3(128), dim3(256), 0, stream>>>(Qb, hend, E);
    k_q0<<<dim3(64), dim3(256), 0, stream>>>(out, Wenc, benc, q0);
    k_efix<<<dim3(512), dim3(256), 0, stream>>>(h_e, q0, E);
    k_rec<<<dim3(128), dim3(256), 0, stream>>>(E, SC);
    k_hedn<<<dim3(32768), dim3(256), 0, stream>>>(h_e, hedn);
    k_soft<<<dim3(4096), dim3(64), 0, stream>>>(SC, alpha);
    k_ce<<<dim3(256), dim3(256), 0, stream>>>(hedn, alpha, out);
    k_dec<<<dim3(64), dim3(256), 0, stream>>>(QDb, Hbf, out);
}

// Round 3
// 1469.358 us; speedup vs baseline: 1.6051x; 1.6051x over previous
//
#include <hip/hip_runtime.h>
#include <math.h>

#define Tn   64
#define BSn  64
#define DIMn 1024
#define EMBn 512
#define SRCn 512
#define G4n  4096   // 4*DIM

typedef __attribute__((ext_vector_type(4))) float  f4;
typedef __attribute__((ext_vector_type(8))) __bf16 b8;
typedef __attribute__((ext_vector_type(4))) __bf16 b4;

__device__ __forceinline__ f4 mfma16(b8 a, b8 b, f4 c) {
    return __builtin_amdgcn_mfma_f32_16x16x32_bf16(a, b, c, 0, 0, 0);
}
__device__ __forceinline__ float sigm(float x) { return 1.0f / (1.0f + __expf(-x)); }
__device__ __forceinline__ b4 tobf4(f4 v) {
    b4 r; r[0]=(__bf16)v[0]; r[1]=(__bf16)v[1]; r[2]=(__bf16)v[2]; r[3]=(__bf16)v[3]; return r;
}
__device__ __forceinline__ f4 fromb4(b4 v) {
    f4 r; r[0]=(float)v[0]; r[1]=(float)v[1]; r[2]=(float)v[2]; r[3]=(float)v[3]; return r;
}

// ---------------------------------------------------------------------------
// Generic 64x64 wave tile GEMM: D[m][n] = sum_k A[m][k] * B[n][k]
// ---------------------------------------------------------------------------
template<int KS>
__device__ __forceinline__ void wave_gemm64(const __bf16* __restrict__ A, int lda,
                                            const __bf16* __restrict__ B, int ldb,
                                            f4 acc[4][4], int lane) {
    const int m = lane & 15, q = lane >> 4;
    const __bf16* Ap = A + (size_t)m * lda + q * 8;
    const __bf16* Bp = B + (size_t)m * ldb + q * 8;
#pragma unroll 2
    for (int ks = 0; ks < KS; ++ks) {
        const int k = ks * 32;
        b8 a0 = *(const b8*)(Ap + k);
        b8 a1 = *(const b8*)(Ap + 16 * lda + k);
        b8 a2 = *(const b8*)(Ap + 32 * lda + k);
        b8 a3 = *(const b8*)(Ap + 48 * lda + k);
        b8 b0 = *(const b8*)(Bp + k);
        b8 b1 = *(const b8*)(Bp + 16 * ldb + k);
        b8 b2 = *(const b8*)(Bp + 32 * ldb + k);
        b8 b3 = *(const b8*)(Bp + 48 * ldb + k);
        acc[0][0]=mfma16(a0,b0,acc[0][0]); acc[0][1]=mfma16(a0,b1,acc[0][1]);
        acc[0][2]=mfma16(a0,b2,acc[0][2]); acc[0][3]=mfma16(a0,b3,acc[0][3]);
        acc[1][0]=mfma16(a1,b0,acc[1][0]); acc[1][1]=mfma16(a1,b1,acc[1][1]);
        acc[1][2]=mfma16(a1,b2,acc[1][2]); acc[1][3]=mfma16(a1,b3,acc[1][3]);
        acc[2][0]=mfma16(a2,b0,acc[2][0]); acc[2][1]=mfma16(a2,b1,acc[2][1]);
        acc[2][2]=mfma16(a2,b2,acc[2][2]); acc[2][3]=mfma16(a2,b3,acc[2][3]);
        acc[3][0]=mfma16(a3,b0,acc[3][0]); acc[3][1]=mfma16(a3,b1,acc[3][1]);
        acc[3][2]=mfma16(a3,b2,acc[3][2]); acc[3][3]=mfma16(a3,b3,acc[3][3]);
    }
}

// ---------------------------------------------------------------------------
// K0a: weights -> bf16, bias sum, h0 -> bf16, zero the barrier counter
// ---------------------------------------------------------------------------
__global__ void k_conv_w(const float* __restrict__ Wih, const float* __restrict__ Whh,
                         const float* __restrict__ Wenc, const float* __restrict__ Wdec,
                         const float* __restrict__ bih, const float* __restrict__ bhh,
                         const float* __restrict__ h0,
                         __bf16* __restrict__ Wihb, __bf16* __restrict__ Whhb,
                         __bf16* __restrict__ Wqdb, float* __restrict__ bsum,
                         __bf16* __restrict__ H0b, unsigned* __restrict__ cnt) {
    size_t stride = (size_t)gridDim.x * blockDim.x;
    for (size_t i = (size_t)blockIdx.x * blockDim.x + threadIdx.x; i < 4194304ull; i += stride) {
        Whhb[i] = (__bf16)Whh[i];
        if (i < 2097152ull) {
            Wihb[i] = (__bf16)Wih[i];
            Wqdb[i] = (__bf16)((i < 1048576ull) ? Wenc[i] : Wdec[i - 1048576ull]);
        }
        if (i < 65536ull) H0b[i] = (__bf16)h0[i];
        if (i < 4096ull)  bsum[i] = bih[i] + bhh[i];
        if (i == 0)       *cnt = 0u;
    }
}

// K0b: embedding gather -> bf16, layout [t*64+b][512]
__global__ __launch_bounds__(128) void k_emb(const int* __restrict__ toks,
                                             const float* __restrict__ Wemb,
                                             __bf16* __restrict__ embb) {
    int tb = blockIdx.x;
    int tok = toks[tb];
    f4 v = *(const f4*)(Wemb + (size_t)tok * EMBn + threadIdx.x * 4);
    *(b4*)(embb + (size_t)tb * EMBn + threadIdx.x * 4) = tobf4(v);
}

// ---------------------------------------------------------------------------
// K1: G_in[tb][r] = emb[tb] . W_ih[r] + b_ih[r] + b_hh[r]   (bf16 out, [tb][4096])
// ---------------------------------------------------------------------------
__global__ __launch_bounds__(256) void k_gin(const __bf16* __restrict__ Wihb,
                                             const __bf16* __restrict__ embb,
                                             const float* __restrict__ bsum,
                                             __bf16* __restrict__ Gbf) {
    int wv = blockIdx.x * 4 + (threadIdx.x >> 6);
    int lane = threadIdx.x & 63, m = lane & 15, q = lane >> 4;
    int Mt = wv >> 6, Nt = wv & 63;
    const f4 Z = {0.f, 0.f, 0.f, 0.f};
    f4 acc[4][4];
#pragma unroll
    for (int i = 0; i < 4; ++i)
#pragma unroll
        for (int j = 0; j < 4; ++j) acc[i][j] = Z;
    wave_gemm64<16>(Wihb + (size_t)Mt * 64 * EMBn, EMBn,
                    embb + (size_t)Nt * 64 * EMBn, EMBn, acc, lane);
#pragma unroll
    for (int mi = 0; mi < 4; ++mi)
#pragma unroll
        for (int ni = 0; ni < 4; ++ni) {
            int r0 = Mt * 64 + mi * 16 + q * 4;
            int tb = Nt * 64 + ni * 16 + m;
            f4 v = acc[mi][ni] + *(const f4*)(bsum + r0);
            *(b4*)(Gbf + (size_t)tb * G4n + r0) = tobf4(v);
        }
}

// ---------------------------------------------------------------------------
// Manual grid barrier: release add, RELAXED spin (no per-poll cache inv),
// single acquire fence once the step is complete.
// ---------------------------------------------------------------------------
__device__ __forceinline__ void gsync(unsigned* cnt, unsigned nb, unsigned& target) {
    __syncthreads();   // compiler emits vmcnt(0) drain before s_barrier
    if (threadIdx.x == 0) {
        __hip_atomic_fetch_add(cnt, 1u, __ATOMIC_RELEASE, __HIP_MEMORY_SCOPE_AGENT);
        target += nb;
        while (__hip_atomic_load(cnt, __ATOMIC_RELAXED, __HIP_MEMORY_SCOPE_AGENT) < target)
            __builtin_amdgcn_s_sleep(1);
        __builtin_amdgcn_fence(__ATOMIC_ACQUIRE, "agent");
    }
    __syncthreads();
}

// ---------------------------------------------------------------------------
// K2: sequential LSTM over t. 64 blocks x 256. Block owns 16 dims x 4 gates.
// W_hh rows staged ONCE into LDS (128 KB) in fragment-linear layout
// (conflict-free ds_read_b128, immune to per-step cache invalidation).
// h fragments preloaded as 32 back-to-back 16B global loads.
// ---------------------------------------------------------------------------
__global__ __launch_bounds__(256, 1) void k_lstm(const __bf16* __restrict__ Whhb,
                                                 const __bf16* __restrict__ Gbf,
                                                 const __bf16* __restrict__ H0b,
                                                 const float* __restrict__ c0,
                                                 __bf16* __restrict__ Hbf,
                                                 float* __restrict__ out,
                                                 unsigned* __restrict__ cnt) {
    __shared__ __attribute__((aligned(16))) __bf16 wlds[4 * 32 * 512];  // 128 KB
    const int tid = threadIdx.x, w = tid >> 6, lane = tid & 63;
    const int m = lane & 15, q = lane >> 4;
    const int dblk = blockIdx.x * 16;

    // stage W_hh fragments: global-coalesced read, fragment-linear LDS write
    for (int i = tid; i < 8192; i += 256) {
        int rr = i >> 7, cc = i & 127;
        int g = rr >> 4, mm = rr & 15;
        int ks = cc >> 2, qq = cc & 3;
        b8 v = *(const b8*)(Whhb + ((size_t)(g * DIMn + dblk + mm)) * DIMn + cc * 8);
        *(b8*)(wlds + ((size_t)((g * 32 + ks) * 64 + qq * 16 + mm)) * 8) = v;
    }
    __syncthreads();

    const int bb = w * 16 + m;        // this thread's batch (D col)
    const int d0 = dblk + q * 4;      // first of this thread's 4 dims (D rows)
    f4 cst = *(const f4*)(c0 + (size_t)bb * DIMn + d0);
    unsigned target = 0;
    const __bf16* wl = wlds + (size_t)lane * 8;   // + (g*32+ks)*512 per frag

    for (int t = 0; t < Tn; ++t) {
        const __bf16* hprev = t ? (Hbf + (size_t)(t - 1) * BSn * DIMn) : H0b;
        const __bf16* hp = hprev + (size_t)bb * DIMn + q * 8;
        b8 harr[32];
#pragma unroll
        for (int ks = 0; ks < 32; ++ks) harr[ks] = *(const b8*)(hp + ks * 32);
        f4 acc[4];
        const __bf16* gp = Gbf + (size_t)(t * BSn + bb) * G4n;
#pragma unroll
        for (int g = 0; g < 4; ++g) acc[g] = fromb4(*(const b4*)(gp + g * DIMn + d0));
#pragma unroll
        for (int ks = 0; ks < 32; ++ks) {
            b8 hb = harr[ks];
            acc[0] = mfma16(*(const b8*)(wl + (size_t)(0 * 32 + ks) * 512), hb, acc[0]);
            acc[1] = mfma16(*(const b8*)(wl + (size_t)(1 * 32 + ks) * 512), hb, acc[1]);
            acc[2] = mfma16(*(const b8*)(wl + (size_t)(2 * 32 + ks) * 512), hb, acc[2]);
            acc[3] = mfma16(*(const b8*)(wl + (size_t)(3 * 32 + ks) * 512), hb, acc[3]);
        }
        f4 hv;
#pragma unroll
        for (int i = 0; i < 4; ++i) {
            float c = sigm(acc[1][i]) * cst[i] + sigm(acc[0][i]) * tanhf(acc[2][i]);
            cst[i] = c;
            hv[i] = sigm(acc[3][i]) * tanhf(c);
        }
        *(f4*)(out + (size_t)(t * BSn + bb) * 3072 + d0) = hv;
        *(b4*)(Hbf + (size_t)(t * BSn + bb) * DIMn + d0) = tobf4(hv);
        if (t != Tn - 1) gsync(cnt, gridDim.x, target);
    }
}

// ---------------------------------------------------------------------------
// K3: Q/QD = H @ [Wenc;Wdec]^T + bias -> Qb/QDb [b][t][d] bf16
// ---------------------------------------------------------------------------
__global__ __launch_bounds__(256) void k_qd(const __bf16* __restrict__ Wqdb,
                                            const __bf16* __restrict__ Hbf,
                                            const float* __restrict__ benc,
                                            const float* __restrict__ bdec,
                                            __bf16* __restrict__ Qb,
                                            __bf16* __restrict__ QDb) {
    int wv = blockIdx.x * 4 + (threadIdx.x >> 6);
    int lane = threadIdx.x & 63, m = lane & 15, q = lane >> 4;
    int Mt = wv >> 6, Nt = wv & 63;
    const f4 Z = {0.f, 0.f, 0.f, 0.f};
    f4 acc[4][4];
#pragma unroll
    for (int i = 0; i < 4; ++i)
#pragma unroll
        for (int j = 0; j < 4; ++j) acc[i][j] = Z;
    wave_gemm64<32>(Wqdb + (size_t)Mt * 64 * DIMn, DIMn,
                    Hbf + (size_t)Nt * 64 * DIMn, DIMn, acc, lane);
#pragma unroll
    for (int mi = 0; mi < 4; ++mi)
#pragma unroll
        for (int ni = 0; ni < 4; ++ni) {
            int dp0 = Mt * 64 + mi * 16 + q * 4;
            int tb = Nt * 64 + ni * 16 + m;
            int t = tb >> 6, b = tb & 63;
            if (dp0 < 1024) {
                f4 v = acc[mi][ni] + *(const f4*)(benc + dp0);
                *(b4*)(Qb + ((size_t)(b * 64 + t)) * DIMn + dp0) = tobf4(v);
            } else {
                f4 v = acc[mi][ni] + *(const f4*)(bdec + (dp0 - 1024));
                *(b4*)(QDb + ((size_t)(b * 64 + t)) * DIMn + (dp0 - 1024)) = tobf4(v);
            }
        }
}

// ---------------------------------------------------------------------------
// K4: E[b][n][t] = Q[b][t] . he_nd[b][n]
// ---------------------------------------------------------------------------
__global__ __launch_bounds__(256) void k_e(const __bf16* __restrict__ Qb,
                                           const __bf16* __restrict__ hend,
                                           float* __restrict__ E) {
    int wv = blockIdx.x * 4 + (threadIdx.x >> 6);   // 512 waves: b(64) x nch(8)
    int lane = threadIdx.x & 63, m = lane & 15, q = lane >> 4;
    int b = wv >> 3, nch = wv & 7;
    const f4 Z = {0.f, 0.f, 0.f, 0.f};
    f4 acc[4][4];
#pragma unroll
    for (int i = 0; i < 4; ++i)
#pragma unroll
        for (int j = 0; j < 4; ++j) acc[i][j] = Z;
    wave_gemm64<32>(Qb + (size_t)b * 64 * DIMn, DIMn,
                    hend + ((size_t)b * SRCn + nch * 64) * DIMn, DIMn, acc, lane);
#pragma unroll
    for (int mi = 0; mi < 4; ++mi)
#pragma unroll
        for (int ni = 0; ni < 4; ++ni) {
            int t0 = mi * 16 + q * 4;
            int n = nch * 64 + ni * 16 + m;
            *(f4*)(E + ((size_t)b * SRCn + n) * 64 + t0) = acc[mi][ni];
        }
}

// K4b: fp32 recompute of q0 = h1 @ Wenc^T + benc (t=0 accuracy insurance)
__global__ __launch_bounds__(256) void k_q0(const float* __restrict__ out,
                                            const float* __restrict__ Wenc,
                                            const float* __restrict__ benc,
                                            float* __restrict__ q0) {
    int b = blockIdx.x;
    __shared__ float h1[1024];
    for (int i = threadIdx.x; i < 1024; i += 256) h1[i] = out[(size_t)b * 3072 + i];
    __syncthreads();
    for (int d = threadIdx.x; d < 1024; d += 256) {
        const float* wr = Wenc + (size_t)d * DIMn;
        float acc = benc[d];
        for (int k = 0; k < 1024; ++k) acc += h1[k] * wr[k];
        q0[(size_t)b * DIMn + d] = acc;
    }
}

// K4c: overwrite E[b][n][0] with fp32 dot q0[b] . h_e[n][b]
__global__ __launch_bounds__(256) void k_efix(const float* __restrict__ he,
                                              const float* __restrict__ q0,
                                              float* __restrict__ E) {
    int b = blockIdx.x >> 3, ng = blockIdx.x & 7;
    __shared__ float q[1024];
    for (int i = threadIdx.x; i < 1024; i += 256) q[i] = q0[(size_t)b * DIMn + i];
    __syncthreads();
    int w = threadIdx.x >> 6, lane = threadIdx.x & 63;
    for (int j = 0; j < 16; ++j) {
        int n = ng * 64 + w * 16 + j;
        const float* x = he + ((size_t)n * BSn + b) * DIMn + lane * 16;
        int k0 = lane * 16;
        float acc = 0.f;
#pragma unroll
        for (int u = 0; u < 16; ++u) acc += x[u] * q[k0 + u];
        for (int off = 32; off; off >>= 1) acc += __shfl_xor(acc, off);
        if (lane == 0) E[((size_t)b * SRCn + n) * 64] = acc;
    }
}

// ---------------------------------------------------------------------------
// K5: online-softmax-over-time recurrence per (b,n); SC[b][t][n]
// ---------------------------------------------------------------------------
__global__ void k_rec(const float* __restrict__ E, float* __restrict__ SC) {
    int idx = blockIdx.x * blockDim.x + threadIdx.x;   // 32768 = b*512+n
    int b = idx >> 9, n = idx & 511;
    const float* ep = E + (size_t)idx * 64;
    float mm = -1e30f, ss = 0.f;
    for (int t = 0; t < 64; ++t) {
        float e = ep[t];
        float m2 = fmaxf(mm, e);
        float s2 = ss * __expf(mm - m2) + __expf(e - m2);
        float sc = (t == 0) ? e : (__expf(e - m2) / s2);
        mm = m2; ss = s2;
        SC[((size_t)(b * 64 + t)) * 512 + n] = sc;
    }
}

// K6: row softmax over n, output bf16 alpha [b][t][n]
__global__ __launch_bounds__(64) void k_soft(const float* __restrict__ SC,
                                             __bf16* __restrict__ alpha) {
    const int row = blockIdx.x, lane = threadIdx.x;
    const float* p = SC + (size_t)row * 512 + lane * 8;
    float v[8];
#pragma unroll
    for (int j = 0; j < 8; ++j) v[j] = p[j];
    float mx = v[0];
#pragma unroll
    for (int j = 1; j < 8; ++j) mx = fmaxf(mx, v[j]);
    for (int off = 32; off; off >>= 1) mx = fmaxf(mx, __shfl_xor(mx, off));
    float s = 0.f;
#pragma unroll
    for (int j = 0; j < 8; ++j) { v[j] = __expf(v[j] - mx); s += v[j]; }
    for (int off = 32; off; off >>= 1) s += __shfl_xor(s, off);
    float inv = 1.f / s;
    b8 o;
#pragma unroll
    for (int j = 0; j < 8; ++j) o[j] = (__bf16)(v[j] * inv);
    *(b8*)(alpha + (size_t)row * 512 + lane * 8) = o;
}

// ---------------------------------------------------------------------------
// K7: h_e [n][b][d] f32 -> hend [b][n][d] bf16 AND hedn [b][d][n] bf16
// (single h_e HBM pass; LDS 32x32 tile transpose)
// ---------------------------------------------------------------------------
__global__ __launch_bounds__(256) void k_hetr(const float* __restrict__ he,
                                              __bf16* __restrict__ hend,
                                              __bf16* __restrict__ hedn) {
    int blk = blockIdx.x;
    int b = blk >> 9, rest = blk & 511, dt = rest >> 4, nt = rest & 15;
    int d0 = dt * 32, n0 = nt * 32;
    __shared__ float tile[32][33];
    int tx = threadIdx.x & 31, ty = threadIdx.x >> 5;
#pragma unroll
    for (int r = 0; r < 4; ++r) {
        int nl = ty + r * 8;
        float v = he[(size_t)(n0 + nl) * (BSn * DIMn) + (size_t)b * DIMn + d0 + tx];
        tile[nl][tx] = v;
        hend[((size_t)b * SRCn + n0 + nl) * DIMn + d0 + tx] = (__bf16)v;
    }
    __syncthreads();
#pragma unroll
    for (int r = 0; r < 4; ++r) {
        int dl = ty + r * 8;
        hedn[((size_t)b * DIMn + d0 + dl) * SRCn + n0 + tx] = (__bf16)tile[tx][dl];
    }
}

// ---------------------------------------------------------------------------
// K8: C_e: out[t][b][1024+d] = sum_n alpha[b][t][n] * h_e[n][b][d]
// ---------------------------------------------------------------------------
__global__ __launch_bounds__(256) void k_ce(const __bf16* __restrict__ hedn,
                                            const __bf16* __restrict__ alpha,
                                            float* __restrict__ out) {
    int wv = blockIdx.x * 4 + (threadIdx.x >> 6);   // 1024 waves: b(64) x dch(16)
    int lane = threadIdx.x & 63, m = lane & 15, q = lane >> 4;
    int b = wv >> 4, dch = wv & 15;
    const f4 Z = {0.f, 0.f, 0.f, 0.f};
    f4 acc[4][4];
#pragma unroll
    for (int i = 0; i < 4; ++i)
#pragma unroll
        for (int j = 0; j < 4; ++j) acc[i][j] = Z;
    wave_gemm64<16>(hedn + ((size_t)b * DIMn + dch * 64) * SRCn, SRCn,
                    alpha + (size_t)b * 64 * SRCn, SRCn, acc, lane);
#pragma unroll
    for (int mi = 0; mi < 4; ++mi)
#pragma unroll
        for (int ni = 0; ni < 4; ++ni) {
            int d0 = dch * 64 + mi * 16 + q * 4;
            int t = ni * 16 + m;
            *(f4*)(out + (size_t)(t * BSn + b) * 3072 + 1024 + d0) = acc[mi][ni];
        }
}

// ---------------------------------------------------------------------------
// K9: decoder self-attention, one block per batch.
// ---------------------------------------------------------------------------
__global__ __launch_bounds__(256) void k_dec(const __bf16* __restrict__ QDb,
                                             const __bf16* __restrict__ Hbf,
                                             float* __restrict__ out) {
    int b = blockIdx.x;
    __shared__ __attribute__((aligned(16))) char smem[46080];
    float*  ed = (float*)smem;               // [64][72] fp32
    __bf16* al = (__bf16*)(smem + 36864);    // [64][72] bf16
    __bf16* ht = (__bf16*)smem;              // [256][72] bf16 phase 3
    int tid = threadIdx.x, w = tid >> 6, lane = tid & 63;
    int m = lane & 15, q = lane >> 4;
    const f4 Z = {0.f, 0.f, 0.f, 0.f};

    { // phase 1: ED[t][t']
        f4 acc[4] = {Z, Z, Z, Z};
        const __bf16* Ap = QDb + ((size_t)(b * 64) + w * 16 + m) * DIMn + q * 8;
        for (int k = 0; k < 1024; k += 32) {
            b8 a = *(const b8*)(Ap + k);
#pragma unroll
            for (int nt = 0; nt < 4; ++nt) {
                const b8 bb = *(const b8*)(Hbf + ((size_t)((nt * 16 + m) * 64) + b) * DIMn + k + q * 8);
                acc[nt] = mfma16(a, bb, acc[nt]);
            }
        }
#pragma unroll
        for (int nt = 0; nt < 4; ++nt)
#pragma unroll
            for (int i = 0; i < 4; ++i)
                ed[(w * 16 + q * 4 + i) * 72 + nt * 16 + m] = acc[nt][i];
    }
    __syncthreads();
    if (tid < 64) { // phase 2: masked row softmax
        int t = tid;
        int nv = t ? t : 1;
        float mx = -1e30f;
        for (int j = 0; j < nv; ++j) mx = fmaxf(mx, ed[t * 72 + j]);
        float s = 0.f;
        for (int j = 0; j < nv; ++j) s += __expf(ed[t * 72 + j] - mx);
        float inv = 1.f / s;
        for (int j = 0; j < 64; ++j)
            al[t * 72 + j] = (__bf16)((j < nv) ? __expf(ed[t * 72 + j] - mx) * inv : 0.f);
    }
    __syncthreads();
    for (int dch = 0; dch < 4; ++dch) { // phase 3: CD = alpha @ H_b
        for (int it = 0; it < 64; ++it)
            ht[tid * 72 + it] = Hbf[((size_t)(it * 64) + b) * DIMn + dch * 256 + tid];
        __syncthreads();
        f4 acc[4][4];
#pragma unroll
        for (int i = 0; i < 4; ++i)
#pragma unroll
            for (int j = 0; j < 4; ++j) acc[i][j] = Z;
#pragma unroll
        for (int kk = 0; kk < 64; kk += 32) {
            b8 a[4], bfr[4];
#pragma unroll
            for (int mi = 0; mi < 4; ++mi)
                a[mi] = *(const b8*)(ht + (size_t)(w * 64 + mi * 16 + m) * 72 + kk + q * 8);
#pragma unroll
            for (int nt = 0; nt < 4; ++nt)
                bfr[nt] = *(const b8*)(al + (size_t)(nt * 16 + m) * 72 + kk + q * 8);
#pragma unroll
            for (int mi = 0; mi < 4; ++mi)
#pragma unroll
                for (int nt = 0; nt < 4; ++nt)
                    acc[mi][nt] = mfma16(a[mi], bfr[nt], acc[mi][nt]);
        }
#pragma unroll
        for (int mi = 0; mi < 4; ++mi)
#pragma unroll
            for (int nt = 0; nt < 4; ++nt) {
                int t = nt * 16 + m;
                int d0 = dch * 256 + w * 64 + mi * 16 + q * 4;
                f4 v = (t == 0) ? Z : acc[mi][nt];
                *(f4*)(out + (size_t)(t * BSn + b) * 3072 + 2048 + d0) = v;
            }
        __syncthreads();
    }
}

// ---------------------------------------------------------------------------
extern "C" void kernel_launch(void* const* d_in, const int* in_sizes, int n_in,
                              void* d_out, int out_size, void* d_ws, size_t ws_size,
                              hipStream_t stream) {
    const int*   toks = (const int*)d_in[0];
    const float* h_e  = (const float*)d_in[1];
    const float* h0   = (const float*)d_in[2];
    const float* c0   = (const float*)d_in[3];
    const float* Wemb = (const float*)d_in[4];
    const float* Wih  = (const float*)d_in[5];
    const float* Whh  = (const float*)d_in[6];
    const float* bih  = (const float*)d_in[7];
    const float* bhh  = (const float*)d_in[8];
    const float* Wenc = (const float*)d_in[9];
    const float* benc = (const float*)d_in[10];
    const float* Wdec = (const float*)d_in[11];
    const float* bdec = (const float*)d_in[12];
    float* out = (float*)d_out;
    char* ws = (char*)d_ws;

    constexpr size_t MB = 1ull << 20;
    // Live-range overlays (launch order enforces safety):
    //   E (9-17 MB) overlays Wihb (dead after k_gin) + Wqdb (dead after k_qd);
    //     k_e (E's first writer) launches after k_qd.
    //   hedn (110-174 MB) overlays Gbf (dead after k_lstm); k_hetr runs after
    //     k_lstm, and NOTHING writes inside 110-174 MB afterwards.
    unsigned* cnt  = (unsigned*)(ws + 0);
    float*  bsum   = (float*)(ws + 1024);
    float*  q0     = (float*)(ws + 256 * 1024);
    __bf16* Whhb   = (__bf16*)(ws + 1 * MB);    // 8 MB
    __bf16* Wihb   = (__bf16*)(ws + 9 * MB);    // 4 MB (dead after k_gin)
    __bf16* Wqdb   = (__bf16*)(ws + 13 * MB);   // 4 MB (dead after k_qd)
    float*  E      = (float*)(ws + 9 * MB);     // 8 MB overlay (written by k_e)
    __bf16* embb   = (__bf16*)(ws + 17 * MB);   // 4 MB
    __bf16* H0b    = (__bf16*)(ws + 21 * MB);   // 128 KB
    __bf16* Hbf    = (__bf16*)(ws + 22 * MB);   // 8 MB
    __bf16* Qb     = (__bf16*)(ws + 30 * MB);   // 8 MB
    __bf16* QDb    = (__bf16*)(ws + 38 * MB);   // 8 MB
    __bf16* hend   = (__bf16*)(ws + 46 * MB);   // 64 MB
    __bf16* Gbf    = (__bf16*)(ws + 110 * MB);  // 32 MB (dead after k_lstm)
    __bf16* hedn   = (__bf16*)(ws + 110 * MB);  // 64 MB overlay (written by k_hetr)
    float*  SC     = (float*)(ws + 174 * MB);   // 8 MB
    __bf16* alpha  = (__bf16*)(ws + 182 * MB);  // 4 MB  -> total 186 MB

    k_conv_w<<<dim3(4096), dim3(256), 0, stream>>>(Wih, Whh, Wenc, Wdec, bih, bhh, h0,
                                                   Wihb, Whhb, Wqdb, bsum, H0b, cnt);
    k_emb<<<dim3(4096), dim3(128), 0, stream>>>(toks, Wemb, embb);
    k_gin<<<dim3(1024), dim3(256), 0, stream>>>(Wihb, embb, bsum, Gbf);
    k_lstm<<<dim3(64), dim3(256), 0, stream>>>(Whhb, Gbf, H0b, c0, Hbf, out, cnt);
    k_hetr<<<dim3(32768), dim3(256), 0, stream>>>(h_e, hend, hedn);
    k_qd<<<dim3(512), dim3(256), 0, stream>>>(Wqdb, Hbf, benc, bdec, Qb, QDb);
    k_e<<<dim3(128), dim3(256), 0, stream>>>(Qb, hend, E);
    k_q0<<<dim3(64), dim3(256), 0, stream>>>(out, Wenc, benc, q0);
    k_efix<<<dim3(512), dim3(256), 0, stream>>>(h_e, q0, E);
    k_rec<<<dim3(128), dim3(256), 0, stream>>>(E, SC);
    k_soft<<<dim3(4096), dim3(64), 0, stream>>>(SC, alpha);
    k_ce<<<dim3(256), dim3(256), 0, stream>>>(hedn, alpha, out);
    k_dec<<<dim3(64), dim3(256), 0, stream>>>(QDb, Hbf, out);
}